// Round 18
// baseline (224.991 us; speedup 1.0000x reference)
//
#include <hip/hip_runtime.h>

#define TT 200
#define BB 256
#define DD 128
#define HH 128
#define NG 896    // 7*H semantic gate dim (gate-major: col = g*128 + u)
#define NGP 1024  // padded pcol = u*8 + g (g=7 pad, never written/read)
#define CH 16     // timesteps per LDS xg chunk

typedef _Float16 half8 __attribute__((ext_vector_type(8)));
typedef _Float16 half4 __attribute__((ext_vector_type(4)));
typedef float float4v __attribute__((ext_vector_type(4)));
typedef int int4v __attribute__((ext_vector_type(4)));

__device__ __forceinline__ float rcpf_(float x) { return __builtin_amdgcn_rcpf(x); }
__device__ __forceinline__ float sigmoidf_(float x) { return rcpf_(1.f + __expf(-x)); }
__device__ __forceinline__ float tanhf_(float x) { return 1.f - 2.f * rcpf_(__expf(2.f * x) + 1.f); }
// softplus(x) = max(x,0) + ln(1+exp(-|x|))
__device__ __forceinline__ float softplusf_(float x) {
  return fmaxf(x, 0.f) + 0.69314718056f * __log2f(1.f + __expf(-fabsf(x)));
}

// prep: blocks [0,28) LDS-tiled Wx transpose -> WxTp[pcol=u*8+g][k];
//       blocks [28,42) W_h i8 per-column quantization (validated r15 version).
__global__ __launch_bounds__(256) void prep_k(const float* __restrict__ Wx,
    const float* __restrict__ Wh, _Float16* __restrict__ WxTp,
    char* __restrict__ WhQ, float* __restrict__ wscale) {
  int bx = blockIdx.x, tid = threadIdx.x;
  if (bx < 28) {  // transpose tile: j in [j0, j0+32), all 128 k
    __shared__ _Float16 Tld[32][136];
    int j0 = bx * 32;
    int jo = tid & 31, kb = tid >> 5;
#pragma unroll
    for (int it = 0; it < 16; ++it) {
      int k = kb + it * 8;
      Tld[jo][k] = (_Float16)Wx[(size_t)k * NG + j0 + jo];  // coalesced over jo
    }
    __syncthreads();
    int g = j0 >> 7, u0 = j0 & 127;
    int jw = tid >> 3, kq = (tid & 7) * 16;
    int pcol = (u0 + jw) * 8 + g;
    *(half8*)&WxTp[(size_t)pcol * DD + kq] = *(const half8*)&Tld[jw][kq];
    *(half8*)&WxTp[(size_t)pcol * DD + kq + 8] = *(const half8*)&Tld[jw][kq + 8];
    return;
  }
  __shared__ float redmax[4][64];
  int c = tid & 63, kq = tid >> 6;
  int col = (bx - 28) * 64 + c;
  float v[32];
  float m = 0.f;
#pragma unroll
  for (int i = 0; i < 32; ++i) {
    v[i] = Wh[(size_t)(kq * 32 + i) * NG + col];
    m = fmaxf(m, fabsf(v[i]));
  }
  redmax[kq][c] = m;
  __syncthreads();
  float mm = fmaxf(fmaxf(redmax[0][c], redmax[1][c]),
                   fmaxf(redmax[2][c], redmax[3][c]));
  mm = mm > 0.f ? mm : 1.f;
  float inv = 127.f * rcpf_(mm);
  char q[32];
#pragma unroll
  for (int i = 0; i < 32; ++i) q[i] = (char)__float2int_rn(v[i] * inv);
#pragma unroll
  for (int i = 0; i < 8; ++i)
    *(int*)&WhQ[(size_t)col * DD + kq * 32 + i * 4] = *(int*)&q[i * 4];
  if (kq == 0) wscale[col] = mm * (1.f / 127.f);
}

// Fused CT-LSTM: r17 champion rec step + in-step xg production into LDS.
// 1 block/sample, 512 threads (8 waves, 2/SIMD — weight residency law).
// Chunked by CH=16 steps; double-buffered xgL. During chunk c (if c+1 exists):
//   s==0: each thread loads 1 float4 of x(chunk c+1) into regs
//   s==1: cvt + write to xld
//   s==2: read A-frags from xld (after barrier)
//   s in [2,8]: gate g=s-2: 4 L2 B-frag loads + 4 f16 MFMAs + 4 LDS b16 writes
// Producer work fills the idle ~60% of the MFMA pipe; the per-step barrier
// gives producer->consumer visibility for free. xg never touches HBM.
__global__ __launch_bounds__(512, 2) void rec_k(const float* __restrict__ x,
    const float* __restrict__ dur, const int* __restrict__ rep,
    const _Float16* __restrict__ WxTp, const char* __restrict__ WhQ,
    const float* __restrict__ wscale, const float* __restrict__ bias,
    float* __restrict__ out) {
  int b = blockIdx.x, j = threadIdx.x;
  int tend = rep[b];
  __shared__ __align__(16) _Float16 xgL[2][CH][NGP];  // 64 KB, [buf][s][u*8+g]
  __shared__ __align__(16) _Float16 xld[CH][DD + 8];  // x chunk staging, f16
  __shared__ __align__(16) char hq[2][HH];            // i8 h, double-buffered
  __shared__ float dlds[TT];
  int w = j >> 6, l = j & 63, lr = l & 15, lg = l >> 4;
  int u = w * 16 + lr;

  // resident i8 W_h B-fragments (56 VGPR) + scales
  int4v wbq[7][2];
#pragma unroll
  for (int g = 0; g < 7; ++g)
#pragma unroll
    for (int m = 0; m < 2; ++m)
      wbq[g][m] = *(const int4v*)(WhQ + (size_t)(g * HH + u) * DD + m * 64 + lg * 16);
  float sg[7];
#pragma unroll
  for (int g = 0; g < 7; ++g) sg[g] = wscale[g * HH + u] * (1.f / 127.f);
  for (int i = j; i < TT; i += 512) dlds[i] = dur[b * TT + i];
  if (lg == 0) { hq[0][u] = (char)0; hq[1][u] = (char)0; }
  float c_s = 0.f, cb_s = 0.f;

  int srow = j >> 5, skq = (j & 31) << 2;  // x staging slot: 16 rows x 32 float4
  // ---- prologue: stage x chunk 0, produce xgL[0] ----
  {
    float4v xv = *(const float4v*)(x + ((size_t)b * TT + srow) * DD + skq);
    half4 h4 = {(_Float16)xv[0], (_Float16)xv[1], (_Float16)xv[2], (_Float16)xv[3]};
    *(half4*)&xld[srow][skq] = h4;
  }
  __syncthreads();
  half8 af[4];
#pragma unroll
  for (int kk = 0; kk < 4; ++kk) af[kk] = *(const half8*)&xld[lr][kk * 32 + lg * 8];
#pragma unroll
  for (int g = 0; g < 7; ++g) {
    half8 bf[4];
#pragma unroll
    for (int kk = 0; kk < 4; ++kk)
      bf[kk] = *(const half8*)(WxTp + ((size_t)u * 8 + g) * DD + kk * 32 + lg * 8);
    float bv = bias[g * HH + u];
    float4v pacc = (float4v){bv, bv, bv, bv};
#pragma unroll
    for (int kk = 0; kk < 4; ++kk)
      pacc = __builtin_amdgcn_mfma_f32_16x16x32_f16(af[kk], bf[kk], pacc, 0, 0, 0);
#pragma unroll
    for (int r = 0; r < 4; ++r)
      xgL[0][lg * 4 + r][u * 8 + g] = (_Float16)pacc[r];
  }
  __syncthreads();  // chunk 0 ready; hq init visible

  float4v xraw = (float4v){0.f, 0.f, 0.f, 0.f};
  for (int base = 0; base <= tend; base += CH) {
    int smax = min(CH - 1, tend - base);
    int hasNext = (base + CH) <= tend;  // block-uniform
    const _Float16* cb_xg = &xgL[(base >> 4) & 1][0][0];
    _Float16* nb_xg = &xgL[((base >> 4) & 1) ^ 1][0][0];
    for (int s = 0; s <= smax; ++s) {
      int T = base + s;
      // ---------- producer slice for chunk c+1 ----------
      if (hasNext) {
        if (s == 0) {
          int tr = min(base + CH + srow, TT - 1);  // clamped rows never consumed
          xraw = *(const float4v*)(x + ((size_t)b * TT + tr) * DD + skq);
        } else if (s == 1) {
          half4 h4 = {(_Float16)xraw[0], (_Float16)xraw[1],
                      (_Float16)xraw[2], (_Float16)xraw[3]};
          *(half4*)&xld[srow][skq] = h4;
        } else if (s == 2) {
#pragma unroll
          for (int kk = 0; kk < 4; ++kk)
            af[kk] = *(const half8*)&xld[lr][kk * 32 + lg * 8];  // after s==1 barrier
        }
        if (s >= 2 && s <= 8) {
          int g = s - 2;
          half8 bf[4];
#pragma unroll
          for (int kk = 0; kk < 4; ++kk)
            bf[kk] = *(const half8*)(WxTp + ((size_t)u * 8 + g) * DD + kk * 32 + lg * 8);
          float bv = bias[g * HH + u];
          float4v pacc = (float4v){bv, bv, bv, bv};
#pragma unroll
          for (int kk = 0; kk < 4; ++kk)
            pacc = __builtin_amdgcn_mfma_f32_16x16x32_f16(af[kk], bf[kk], pacc, 0, 0, 0);
#pragma unroll
          for (int r = 0; r < 4; ++r)
            nb_xg[(lg * 4 + r) * NGP + u * 8 + g] = (_Float16)pacc[r];
        }
      }
      // ---------- rec step (r17 champion body; xv from LDS) ----------
      {
        half8 xv = *(const half8*)(cb_xg + s * NGP + u * 8);
        float dt = dlds[T];
        int pin = s & 1;  // base % 16 == 0 -> T&1 == s&1
        const char* hin = hq[pin];
        char* hout = hq[pin ^ 1];
        int4v aq0 = *(const int4v*)&hin[lg * 16];
        int4v aq1 = *(const int4v*)&hin[64 + lg * 16];
        int4v acc[7];
#pragma unroll
        for (int g = 0; g < 7; ++g) acc[g] = (int4v){0, 0, 0, 0};
#pragma unroll
        for (int g = 0; g < 7; ++g)
          acc[g] = __builtin_amdgcn_mfma_i32_16x16x64_i8(aq0, wbq[g][0], acc[g], 0, 0, 0);
#pragma unroll
        for (int g = 0; g < 7; ++g)
          acc[g] = __builtin_amdgcn_mfma_i32_16x16x64_i8(aq1, wbq[g][1], acc[g], 0, 0, 0);
        float gv[7];
#pragma unroll
        for (int g = 0; g < 7; ++g)
          gv[g] = (float)acc[g][0] * sg[g] + (float)xv[g];
        float iv = sigmoidf_(gv[0]), fv = sigmoidf_(gv[1]);
        float zv = tanhf_(gv[2]), ov = sigmoidf_(gv[3]);
        float ibv = sigmoidf_(gv[4]), fbv = sigmoidf_(gv[5]);
        float dv = softplusf_(gv[6]);
        float cc = fv * c_s + iv * zv;
        cb_s = fbv * cb_s + ibv * zv;
        float cn = cb_s + (cc - cb_s) * __expf(-dv * dt);
        float hn = ov * tanhf_(cn);
        c_s = cn;
        char hb = (char)__float2int_rn(hn * 127.f);
        if (lg == 0) {
          if (T == tend) {
            out[b * HH + u] = hn;
            out[BB * HH + b * HH + u] = cn;
          }
          hout[u] = hb;
        }
        __syncthreads();
      }
    }
  }
}

extern "C" void kernel_launch(void* const* d_in, const int* in_sizes, int n_in,
                              void* d_out, int out_size, void* d_ws, size_t ws_size,
                              hipStream_t stream) {
  const float* x = (const float*)d_in[0];
  const float* dur = (const float*)d_in[1];
  const int* rep = (const int*)d_in[2];
  const float* Wx = (const float*)d_in[3];
  const float* Wh = (const float*)d_in[4];
  const float* bias = (const float*)d_in[5];
  float* out = (float*)d_out;
  char* ws = (char*)d_ws;

  size_t off = 0;
  _Float16* WxTp = (_Float16*)(ws + off); off += (size_t)NGP * DD * 2;
  char* WhQ = (char*)(ws + off); off += (size_t)NG * DD;
  off = (off + 255) & ~(size_t)255;
  float* wscale = (float*)(ws + off); off += (size_t)NG * 4;

  hipLaunchKernelGGL(prep_k, dim3(28 + NG / 64), dim3(256), 0, stream,
                     Wx, Wh, WxTp, WhQ, wscale);
  hipLaunchKernelGGL(rec_k, dim3(BB), dim3(512), 0, stream,
                     x, dur, rep, WxTp, WhQ, wscale, bias, out);
}

// Round 19
// 162.940 us; speedup vs baseline: 1.3808x; 1.3808x over previous
//
#include <hip/hip_runtime.h>

#define TT 200
#define BB 256
#define DD 128
#define HH 128
#define NG 896     // 7*H semantic gate dim (gate-major: col = g*128 + u)
#define NGP 1024   // padded pcol = u*8 + g (g=7 pad)
#define NGP2 1032  // LDS xg row halfs (+8 pad, keeps 16B align, shifts banks)
#define CH 16      // timesteps per LDS xg chunk

typedef _Float16 half8 __attribute__((ext_vector_type(8)));
typedef _Float16 half4 __attribute__((ext_vector_type(4)));
typedef float float4v __attribute__((ext_vector_type(4)));
typedef int int4v __attribute__((ext_vector_type(4)));

__device__ __forceinline__ float rcpf_(float x) { return __builtin_amdgcn_rcpf(x); }
__device__ __forceinline__ float sigmoidf_(float x) { return rcpf_(1.f + __expf(-x)); }
__device__ __forceinline__ float tanhf_(float x) { return 1.f - 2.f * rcpf_(__expf(2.f * x) + 1.f); }
// softplus(x) = max(x,0) + ln(1+exp(-|x|))
__device__ __forceinline__ float softplusf_(float x) {
  return fmaxf(x, 0.f) + 0.69314718056f * __log2f(1.f + __expf(-fabsf(x)));
}

// prep: blocks [0,28) LDS-tiled Wx transpose -> WxTp[pcol=u*8+g][k];
//       blocks [28,42) W_h i8 per-column quantization (validated r15 version).
__global__ __launch_bounds__(256) void prep_k(const float* __restrict__ Wx,
    const float* __restrict__ Wh, _Float16* __restrict__ WxTp,
    char* __restrict__ WhQ, float* __restrict__ wscale) {
  int bx = blockIdx.x, tid = threadIdx.x;
  if (bx < 28) {
    __shared__ _Float16 Tld[32][136];
    int j0 = bx * 32;
    int jo = tid & 31, kb = tid >> 5;
#pragma unroll
    for (int it = 0; it < 16; ++it) {
      int k = kb + it * 8;
      Tld[jo][k] = (_Float16)Wx[(size_t)k * NG + j0 + jo];  // coalesced over jo
    }
    __syncthreads();
    int g = j0 >> 7, u0 = j0 & 127;
    int jw = tid >> 3, kq = (tid & 7) * 16;
    int pcol = (u0 + jw) * 8 + g;
    *(half8*)&WxTp[(size_t)pcol * DD + kq] = *(const half8*)&Tld[jw][kq];
    *(half8*)&WxTp[(size_t)pcol * DD + kq + 8] = *(const half8*)&Tld[jw][kq + 8];
    return;
  }
  __shared__ float redmax[4][64];
  int c = tid & 63, kq = tid >> 6;
  int col = (bx - 28) * 64 + c;
  float v[32];
  float m = 0.f;
#pragma unroll
  for (int i = 0; i < 32; ++i) {
    v[i] = Wh[(size_t)(kq * 32 + i) * NG + col];
    m = fmaxf(m, fabsf(v[i]));
  }
  redmax[kq][c] = m;
  __syncthreads();
  float mm = fmaxf(fmaxf(redmax[0][c], redmax[1][c]),
                   fmaxf(redmax[2][c], redmax[3][c]));
  mm = mm > 0.f ? mm : 1.f;
  float inv = 127.f * rcpf_(mm);
  char q[32];
#pragma unroll
  for (int i = 0; i < 32; ++i) q[i] = (char)__float2int_rn(v[i] * inv);
#pragma unroll
  for (int i = 0; i < 8; ++i)
    *(int*)&WhQ[(size_t)col * DD + kq * 32 + i * 4] = *(int*)&q[i * 4];
  if (kq == 0) wscale[col] = mm * (1.f / 127.f);
}

// Fused CT-LSTM, producer fixed: W_x frags + bias REGISTER-RESIDENT (no VMEM
// in the loop), per-gate results packed in registers and written as 4 aligned
// ds_write_b128 per chunk (vs r18's 28 scattered b16 = 8-way conflicts).
// 1 block/sample, 512 threads (8 waves, 2/SIMD: weight-residency law).
// Chunk c slots (block-uniform): s0 load x(c+1)->reg; s1 write xld; s2 read
// A-frags; s3..9 gate g=s-3: 4 resident-MFMA + pack; s10: 4 b128 writes.
__global__ __launch_bounds__(512, 2) void rec_k(const float* __restrict__ x,
    const float* __restrict__ dur, const int* __restrict__ rep,
    const _Float16* __restrict__ WxTp, const char* __restrict__ WhQ,
    const float* __restrict__ wscale, const float* __restrict__ bias,
    float* __restrict__ out) {
  int b = blockIdx.x, j = threadIdx.x;
  int tend = rep[b];
  __shared__ __align__(16) _Float16 xgL[2][CH][NGP2];  // 66 KB
  __shared__ __align__(16) _Float16 xld[CH][DD + 8];
  __shared__ __align__(16) char hq[2][HH];
  __shared__ float dlds[TT];
  int w = j >> 6, l = j & 63, lr = l & 15, lg = l >> 4;
  int u = w * 16 + lr;

  // resident i8 W_h B-frags (56 VGPR) + f16 W_x B-frags (56 VGPR) + scales
  int4v wbq[7][2];
  half8 wbx[7][4];
  float sg[7], bias_r[7];
#pragma unroll
  for (int g = 0; g < 7; ++g) {
#pragma unroll
    for (int m = 0; m < 2; ++m)
      wbq[g][m] = *(const int4v*)(WhQ + (size_t)(g * HH + u) * DD + m * 64 + lg * 16);
#pragma unroll
    for (int kk = 0; kk < 4; ++kk)
      wbx[g][kk] = *(const half8*)(WxTp + ((size_t)u * 8 + g) * DD + kk * 32 + lg * 8);
    sg[g] = wscale[g * HH + u] * (1.f / 127.f);
    bias_r[g] = bias[g * HH + u];
  }
  for (int i = j; i < TT; i += 512) dlds[i] = dur[b * TT + i];
  if (lg == 0) { hq[0][u] = (char)0; hq[1][u] = (char)0; }
  float c_s = 0.f, cb_s = 0.f;

  int srow = j >> 5, skq = (j & 31) << 2;  // x staging: 16 rows x 32 float4
  half8 af[4];
  half8 xo0 = {}, xo1 = {}, xo2 = {}, xo3 = {};
  float4v xraw = (float4v){0.f, 0.f, 0.f, 0.f};

#define PRODG(G)                                                                 \
  do {                                                                           \
    float bv = bias_r[(G)];                                                      \
    float4v pacc = (float4v){bv, bv, bv, bv};                                    \
    _Pragma("unroll") for (int kk = 0; kk < 4; ++kk)                             \
        pacc = __builtin_amdgcn_mfma_f32_16x16x32_f16(af[kk], wbx[(G)][kk],      \
                                                      pacc, 0, 0, 0);            \
    xo0[(G)] = (_Float16)pacc[0];                                                \
    xo1[(G)] = (_Float16)pacc[1];                                                \
    xo2[(G)] = (_Float16)pacc[2];                                                \
    xo3[(G)] = (_Float16)pacc[3];                                                \
  } while (0)

#define XO_WRITE(DST)                                                            \
  do {                                                                           \
    *(half8*)((DST) + (lg * 4 + 0) * NGP2 + u * 8) = xo0;                        \
    *(half8*)((DST) + (lg * 4 + 1) * NGP2 + u * 8) = xo1;                        \
    *(half8*)((DST) + (lg * 4 + 2) * NGP2 + u * 8) = xo2;                        \
    *(half8*)((DST) + (lg * 4 + 3) * NGP2 + u * 8) = xo3;                        \
  } while (0)

  // ---- prologue: stage x chunk 0, produce xgL[0] ----
  {
    float4v xv = *(const float4v*)(x + ((size_t)b * TT + srow) * DD + skq);
    half4 h4 = {(_Float16)xv[0], (_Float16)xv[1], (_Float16)xv[2], (_Float16)xv[3]};
    *(half4*)&xld[srow][skq] = h4;
  }
  __syncthreads();
#pragma unroll
  for (int kk = 0; kk < 4; ++kk) af[kk] = *(const half8*)&xld[lr][kk * 32 + lg * 8];
  PRODG(0); PRODG(1); PRODG(2); PRODG(3); PRODG(4); PRODG(5); PRODG(6);
  XO_WRITE(&xgL[0][0][0]);
  __syncthreads();  // chunk 0 ready; hq init visible

#define PSLICE(S)                                                                \
  do {                                                                           \
    if ((S) == 0) {                                                              \
      int tr = min(base + CH + srow, TT - 1);                                    \
      xraw = *(const float4v*)(x + ((size_t)b * TT + tr) * DD + skq);            \
    } else if ((S) == 1) {                                                       \
      half4 h4 = {(_Float16)xraw[0], (_Float16)xraw[1],                          \
                  (_Float16)xraw[2], (_Float16)xraw[3]};                         \
      *(half4*)&xld[srow][skq] = h4;                                             \
    } else if ((S) == 2) {                                                       \
      _Pragma("unroll") for (int kk = 0; kk < 4; ++kk)                           \
          af[kk] = *(const half8*)&xld[lr][kk * 32 + lg * 8];                    \
    } else if ((S) >= 3 && (S) <= 9) {                                           \
      PRODG((S) - 3);                                                            \
    } else if ((S) == 10) {                                                      \
      XO_WRITE(nb_xg);                                                           \
    }                                                                            \
  } while (0)

#define FSTEP(S)                                                                 \
  if ((S) <= smax) {                                                             \
    if (hasNext) PSLICE(S);                                                      \
    int T = base + (S);                                                          \
    half8 xv = *(const half8*)(cb_xg + (S) * NGP2 + u * 8);                      \
    float dt = dlds[T];                                                          \
    const char* hin = hq[(S) & 1];                                               \
    char* hout = hq[((S) & 1) ^ 1];                                              \
    int4v aq0 = *(const int4v*)&hin[lg * 16];                                    \
    int4v aq1 = *(const int4v*)&hin[64 + lg * 16];                               \
    int4v acc[7];                                                                \
    _Pragma("unroll") for (int g = 0; g < 7; ++g) acc[g] = (int4v){0, 0, 0, 0};  \
    _Pragma("unroll") for (int g = 0; g < 7; ++g)                                \
        acc[g] = __builtin_amdgcn_mfma_i32_16x16x64_i8(aq0, wbq[g][0], acc[g], 0, 0, 0); \
    _Pragma("unroll") for (int g = 0; g < 7; ++g)                                \
        acc[g] = __builtin_amdgcn_mfma_i32_16x16x64_i8(aq1, wbq[g][1], acc[g], 0, 0, 0); \
    float gv[7];                                                                 \
    _Pragma("unroll") for (int g = 0; g < 7; ++g)                                \
        gv[g] = (float)acc[g][0] * sg[g] + (float)xv[g];                         \
    float iv = sigmoidf_(gv[0]), fv = sigmoidf_(gv[1]);                          \
    float zv = tanhf_(gv[2]), ov = sigmoidf_(gv[3]);                             \
    float ibv = sigmoidf_(gv[4]), fbv = sigmoidf_(gv[5]);                        \
    float dv = softplusf_(gv[6]);                                                \
    float cc = fv * c_s + iv * zv;                                               \
    cb_s = fbv * cb_s + ibv * zv;                                                \
    float cn = cb_s + (cc - cb_s) * __expf(-dv * dt);                            \
    float hn = ov * tanhf_(cn);                                                  \
    c_s = cn;                                                                    \
    char hb = (char)__float2int_rn(hn * 127.f);                                  \
    if (lg == 0) {                                                               \
      if (T == tend) {                                                           \
        out[b * HH + u] = hn;                                                    \
        out[BB * HH + b * HH + u] = cn;                                          \
      }                                                                          \
      hout[u] = hb;                                                              \
    }                                                                            \
    __syncthreads();                                                             \
  }

  for (int base = 0; base <= tend; base += CH) {
    int smax = min(CH - 1, tend - base);
    int hasNext = (base + CH) <= tend;  // block-uniform
    const _Float16* cb_xg = &xgL[(base >> 4) & 1][0][0];
    _Float16* nb_xg = &xgL[((base >> 4) & 1) ^ 1][0][0];
    FSTEP(0)  FSTEP(1)  FSTEP(2)  FSTEP(3)
    FSTEP(4)  FSTEP(5)  FSTEP(6)  FSTEP(7)
    FSTEP(8)  FSTEP(9)  FSTEP(10) FSTEP(11)
    FSTEP(12) FSTEP(13) FSTEP(14) FSTEP(15)
  }
#undef FSTEP
#undef PSLICE
#undef XO_WRITE
#undef PRODG
}

extern "C" void kernel_launch(void* const* d_in, const int* in_sizes, int n_in,
                              void* d_out, int out_size, void* d_ws, size_t ws_size,
                              hipStream_t stream) {
  const float* x = (const float*)d_in[0];
  const float* dur = (const float*)d_in[1];
  const int* rep = (const int*)d_in[2];
  const float* Wx = (const float*)d_in[3];
  const float* Wh = (const float*)d_in[4];
  const float* bias = (const float*)d_in[5];
  float* out = (float*)d_out;
  char* ws = (char*)d_ws;

  size_t off = 0;
  _Float16* WxTp = (_Float16*)(ws + off); off += (size_t)NGP * DD * 2;
  char* WhQ = (char*)(ws + off); off += (size_t)NG * DD;
  off = (off + 255) & ~(size_t)255;
  float* wscale = (float*)(ws + off); off += (size_t)NG * 4;

  hipLaunchKernelGGL(prep_k, dim3(28 + NG / 64), dim3(256), 0, stream,
                     Wx, Wh, WxTp, WhQ, wscale);
  hipLaunchKernelGGL(rec_k, dim3(BB), dim3(512), 0, stream,
                     x, dur, rep, WxTp, WhQ, wscale, bias, out);
}

// Round 20
// 156.164 us; speedup vs baseline: 1.4407x; 1.0434x over previous
//
#include <hip/hip_runtime.h>

#define TT 200
#define BB 256
#define DD 128
#define HH 128
#define NG 896     // 7*H semantic gate dim (gate-major: col = g*128 + u)
#define NGP 1024   // padded pcol = u*8 + g (g=7 pad)
#define NGP2 1032  // LDS xg row halfs (+8 pad)
#define CH 16      // timesteps per LDS xg chunk

typedef _Float16 half8 __attribute__((ext_vector_type(8)));
typedef _Float16 half4 __attribute__((ext_vector_type(4)));
typedef float float4v __attribute__((ext_vector_type(4)));
typedef int int4v __attribute__((ext_vector_type(4)));

__device__ __forceinline__ float rcpf_(float x) { return __builtin_amdgcn_rcpf(x); }
__device__ __forceinline__ float sigmoidf_(float x) { return rcpf_(1.f + __expf(-x)); }
__device__ __forceinline__ float tanhf_(float x) { return 1.f - 2.f * rcpf_(__expf(2.f * x) + 1.f); }
// softplus(x) = max(x,0) + ln(1+exp(-|x|))
__device__ __forceinline__ float softplusf_(float x) {
  return fmaxf(x, 0.f) + 0.69314718056f * __log2f(1.f + __expf(-fabsf(x)));
}

// prep: blocks [0,28) LDS-tiled Wx transpose -> WxTp[pcol=u*8+g][k];
//       blocks [28,42) W_h i8 per-column quantization (validated r15 version).
__global__ __launch_bounds__(256) void prep_k(const float* __restrict__ Wx,
    const float* __restrict__ Wh, _Float16* __restrict__ WxTp,
    char* __restrict__ WhQ, float* __restrict__ wscale) {
  int bx = blockIdx.x, tid = threadIdx.x;
  if (bx < 28) {
    __shared__ _Float16 Tld[32][136];
    int j0 = bx * 32;
    int jo = tid & 31, kb = tid >> 5;
#pragma unroll
    for (int it = 0; it < 16; ++it) {
      int k = kb + it * 8;
      Tld[jo][k] = (_Float16)Wx[(size_t)k * NG + j0 + jo];  // coalesced over jo
    }
    __syncthreads();
    int g = j0 >> 7, u0 = j0 & 127;
    int jw = tid >> 3, kq = (tid & 7) * 16;
    int pcol = (u0 + jw) * 8 + g;
    *(half8*)&WxTp[(size_t)pcol * DD + kq] = *(const half8*)&Tld[jw][kq];
    *(half8*)&WxTp[(size_t)pcol * DD + kq + 8] = *(const half8*)&Tld[jw][kq + 8];
    return;
  }
  __shared__ float redmax[4][64];
  int c = tid & 63, kq = tid >> 6;
  int col = (bx - 28) * 64 + c;
  float v[32];
  float m = 0.f;
#pragma unroll
  for (int i = 0; i < 32; ++i) {
    v[i] = Wh[(size_t)(kq * 32 + i) * NG + col];
    m = fmaxf(m, fabsf(v[i]));
  }
  redmax[kq][c] = m;
  __syncthreads();
  float mm = fmaxf(fmaxf(redmax[0][c], redmax[1][c]),
                   fmaxf(redmax[2][c], redmax[3][c]));
  mm = mm > 0.f ? mm : 1.f;
  float inv = 127.f * rcpf_(mm);
  char q[32];
#pragma unroll
  for (int i = 0; i < 32; ++i) q[i] = (char)__float2int_rn(v[i] * inv);
#pragma unroll
  for (int i = 0; i < 8; ++i)
    *(int*)&WhQ[(size_t)col * DD + kq * 32 + i * 4] = *(int*)&q[i * 4];
  if (kq == 0) wscale[col] = mm * (1.f / 127.f);
}

// Fused CT-LSTM, spill-free: W_x B-frags PREFETCHED one slot ahead into two
// alternating 16-reg buffers (r19's 56-reg resident wbx overflowed the arch-
// VGPR partition -> 22.8 MB scratch). i8 rec accs split 4+3 to cut live regs.
// 1 block/sample, 512 threads (8 waves, 2/SIMD: weight-residency law).
// Chunk slots: s0 load x(c+1); s1 write xld; s2 read af + issue bf(g0);
// s3..9: PRODG(g=s-3) with bf[s&1], issue bf(g=s-2) into bf[(s&1)^1];
// s10: 4x ds_write_b128 of packed xo.
__global__ __launch_bounds__(512, 2) void rec_k(const float* __restrict__ x,
    const float* __restrict__ dur, const int* __restrict__ rep,
    const _Float16* __restrict__ WxTp, const char* __restrict__ WhQ,
    const float* __restrict__ wscale, const float* __restrict__ bias,
    float* __restrict__ out) {
  int b = blockIdx.x, j = threadIdx.x;
  int tend = rep[b];
  __shared__ __align__(16) _Float16 xgL[2][CH][NGP2];  // 66 KB
  __shared__ __align__(16) _Float16 xld[CH][DD + 8];
  __shared__ __align__(16) char hq[2][HH];
  __shared__ float dlds[TT];
  int w = j >> 6, l = j & 63, lr = l & 15, lg = l >> 4;
  int u = w * 16 + lr;

  // resident i8 W_h B-frags (56 VGPR) + scales + bias
  int4v wbq[7][2];
  float sg[7], bias_r[7];
#pragma unroll
  for (int g = 0; g < 7; ++g) {
#pragma unroll
    for (int m = 0; m < 2; ++m)
      wbq[g][m] = *(const int4v*)(WhQ + (size_t)(g * HH + u) * DD + m * 64 + lg * 16);
    sg[g] = wscale[g * HH + u] * (1.f / 127.f);
    bias_r[g] = bias[g * HH + u];
  }
  for (int i = j; i < TT; i += 512) dlds[i] = dur[b * TT + i];
  if (lg == 0) { hq[0][u] = (char)0; hq[1][u] = (char)0; }
  float c_s = 0.f, cb_s = 0.f;

  int srow = j >> 5, skq = (j & 31) << 2;  // x staging: 16 rows x 32 float4
  half8 af[4];
  half8 bf0[4], bf1[4];  // alternating W_x B-frag prefetch buffers
  half8 xo0 = {}, xo1 = {}, xo2 = {}, xo3 = {};
  float4v xraw = (float4v){0.f, 0.f, 0.f, 0.f};

#define WXLOAD(G, BUF)                                                           \
  do {                                                                           \
    _Pragma("unroll") for (int kk = 0; kk < 4; ++kk)                             \
        BUF[kk] = *(const half8*)(WxTp + ((size_t)u * 8 + (G)) * DD +            \
                                  kk * 32 + lg * 8);                             \
  } while (0)

#define PRODG(G, BUF)                                                            \
  do {                                                                           \
    float bv = bias_r[(G)];                                                      \
    float4v pacc = (float4v){bv, bv, bv, bv};                                    \
    _Pragma("unroll") for (int kk = 0; kk < 4; ++kk)                             \
        pacc = __builtin_amdgcn_mfma_f32_16x16x32_f16(af[kk], BUF[kk],           \
                                                      pacc, 0, 0, 0);            \
    xo0[(G)] = (_Float16)pacc[0];                                                \
    xo1[(G)] = (_Float16)pacc[1];                                                \
    xo2[(G)] = (_Float16)pacc[2];                                                \
    xo3[(G)] = (_Float16)pacc[3];                                                \
  } while (0)

#define XO_WRITE(DST)                                                            \
  do {                                                                           \
    *(half8*)((DST) + (lg * 4 + 0) * NGP2 + u * 8) = xo0;                        \
    *(half8*)((DST) + (lg * 4 + 1) * NGP2 + u * 8) = xo1;                        \
    *(half8*)((DST) + (lg * 4 + 2) * NGP2 + u * 8) = xo2;                        \
    *(half8*)((DST) + (lg * 4 + 3) * NGP2 + u * 8) = xo3;                        \
  } while (0)

  // ---- prologue: stage x chunk 0, produce xgL[0] (sequential, one-time) ----
  {
    float4v xv = *(const float4v*)(x + ((size_t)b * TT + srow) * DD + skq);
    half4 h4 = {(_Float16)xv[0], (_Float16)xv[1], (_Float16)xv[2], (_Float16)xv[3]};
    *(half4*)&xld[srow][skq] = h4;
  }
  __syncthreads();
#pragma unroll
  for (int kk = 0; kk < 4; ++kk) af[kk] = *(const half8*)&xld[lr][kk * 32 + lg * 8];
  WXLOAD(0, bf0); PRODG(0, bf0);
  WXLOAD(1, bf1); PRODG(1, bf1);
  WXLOAD(2, bf0); PRODG(2, bf0);
  WXLOAD(3, bf1); PRODG(3, bf1);
  WXLOAD(4, bf0); PRODG(4, bf0);
  WXLOAD(5, bf1); PRODG(5, bf1);
  WXLOAD(6, bf0); PRODG(6, bf0);
  XO_WRITE(&xgL[0][0][0]);
  __syncthreads();  // chunk 0 ready; hq init visible

  // Producer slice at compile-time slot S (only when hasNext):
  //  PRODG at slot S (3..9) reads bf[S&1]; load at slot S (2..8) fills
  //  bf[(S&1)^1] with gate S-2 — one-slot lead, latency hidden by rec body.
#define PSLICE(S)                                                                \
  do {                                                                           \
    if ((S) == 0) {                                                              \
      int tr = min(base + CH + srow, TT - 1);                                    \
      xraw = *(const float4v*)(x + ((size_t)b * TT + tr) * DD + skq);            \
    } else if ((S) == 1) {                                                       \
      half4 h4 = {(_Float16)xraw[0], (_Float16)xraw[1],                          \
                  (_Float16)xraw[2], (_Float16)xraw[3]};                         \
      *(half4*)&xld[srow][skq] = h4;                                             \
    } else if ((S) == 2) {                                                       \
      _Pragma("unroll") for (int kk = 0; kk < 4; ++kk)                           \
          af[kk] = *(const half8*)&xld[lr][kk * 32 + lg * 8];                    \
      WXLOAD(0, bf1);                                                            \
    } else if ((S) >= 3 && (S) <= 9) {                                           \
      if (((S) & 1) == 1) {                                                      \
        PRODG((S) - 3, bf1);                                                     \
        if ((S) <= 8) WXLOAD((S) - 2, bf0);                                      \
      } else {                                                                   \
        PRODG((S) - 3, bf0);                                                     \
        if ((S) <= 8) WXLOAD((S) - 2, bf1);                                      \
      }                                                                          \
    } else if ((S) == 10) {                                                      \
      XO_WRITE(nb_xg);                                                           \
    }                                                                            \
  } while (0)

#define FSTEP(S)                                                                 \
  if ((S) <= smax) {                                                             \
    if (hasNext) PSLICE(S);                                                      \
    int T = base + (S);                                                          \
    half8 xv = *(const half8*)(cb_xg + (S) * NGP2 + u * 8);                      \
    float dt = dlds[T];                                                          \
    const char* hin = hq[(S) & 1];                                               \
    char* hout = hq[((S) & 1) ^ 1];                                              \
    int4v aq0 = *(const int4v*)&hin[lg * 16];                                    \
    int4v aq1 = *(const int4v*)&hin[64 + lg * 16];                               \
    float gv[7];                                                                 \
    {                                                                            \
      int4v acc[4];                                                              \
      _Pragma("unroll") for (int g = 0; g < 4; ++g) {                            \
        acc[g] = (int4v){0, 0, 0, 0};                                            \
        acc[g] = __builtin_amdgcn_mfma_i32_16x16x64_i8(aq0, wbq[g][0], acc[g], 0, 0, 0); \
        acc[g] = __builtin_amdgcn_mfma_i32_16x16x64_i8(aq1, wbq[g][1], acc[g], 0, 0, 0); \
      }                                                                          \
      _Pragma("unroll") for (int g = 0; g < 4; ++g)                              \
          gv[g] = (float)acc[g][0] * sg[g] + (float)xv[g];                       \
    }                                                                            \
    {                                                                            \
      int4v acc[3];                                                              \
      _Pragma("unroll") for (int g = 0; g < 3; ++g) {                            \
        acc[g] = (int4v){0, 0, 0, 0};                                            \
        acc[g] = __builtin_amdgcn_mfma_i32_16x16x64_i8(aq0, wbq[g + 4][0], acc[g], 0, 0, 0); \
        acc[g] = __builtin_amdgcn_mfma_i32_16x16x64_i8(aq1, wbq[g + 4][1], acc[g], 0, 0, 0); \
      }                                                                          \
      _Pragma("unroll") for (int g = 0; g < 3; ++g)                              \
          gv[g + 4] = (float)acc[g][0] * sg[g + 4] + (float)xv[g + 4];           \
    }                                                                            \
    float iv = sigmoidf_(gv[0]), fv = sigmoidf_(gv[1]);                          \
    float zv = tanhf_(gv[2]), ov = sigmoidf_(gv[3]);                             \
    float ibv = sigmoidf_(gv[4]), fbv = sigmoidf_(gv[5]);                        \
    float dv = softplusf_(gv[6]);                                                \
    float cc = fv * c_s + iv * zv;                                               \
    cb_s = fbv * cb_s + ibv * zv;                                                \
    float cn = cb_s + (cc - cb_s) * __expf(-dv * dt);                            \
    float hn = ov * tanhf_(cn);                                                  \
    c_s = cn;                                                                    \
    char hb = (char)__float2int_rn(hn * 127.f);                                  \
    if (lg == 0) {                                                               \
      if (T == tend) {                                                           \
        out[b * HH + u] = hn;                                                    \
        out[BB * HH + b * HH + u] = cn;                                          \
      }                                                                          \
      hout[u] = hb;                                                              \
    }                                                                            \
    __syncthreads();                                                             \
  }

  for (int base = 0; base <= tend; base += CH) {
    int smax = min(CH - 1, tend - base);
    int hasNext = (base + CH) <= tend;  // block-uniform
    const _Float16* cb_xg = &xgL[(base >> 4) & 1][0][0];
    _Float16* nb_xg = &xgL[((base >> 4) & 1) ^ 1][0][0];
    FSTEP(0)  FSTEP(1)  FSTEP(2)  FSTEP(3)
    FSTEP(4)  FSTEP(5)  FSTEP(6)  FSTEP(7)
    FSTEP(8)  FSTEP(9)  FSTEP(10) FSTEP(11)
    FSTEP(12) FSTEP(13) FSTEP(14) FSTEP(15)
  }
#undef FSTEP
#undef PSLICE
#undef XO_WRITE
#undef PRODG
#undef WXLOAD
}

extern "C" void kernel_launch(void* const* d_in, const int* in_sizes, int n_in,
                              void* d_out, int out_size, void* d_ws, size_t ws_size,
                              hipStream_t stream) {
  const float* x = (const float*)d_in[0];
  const float* dur = (const float*)d_in[1];
  const int* rep = (const int*)d_in[2];
  const float* Wx = (const float*)d_in[3];
  const float* Wh = (const float*)d_in[4];
  const float* bias = (const float*)d_in[5];
  float* out = (float*)d_out;
  char* ws = (char*)d_ws;

  size_t off = 0;
  _Float16* WxTp = (_Float16*)(ws + off); off += (size_t)NGP * DD * 2;
  char* WhQ = (char*)(ws + off); off += (size_t)NG * DD;
  off = (off + 255) & ~(size_t)255;
  float* wscale = (float*)(ws + off); off += (size_t)NG * 4;

  hipLaunchKernelGGL(prep_k, dim3(28 + NG / 64), dim3(256), 0, stream,
                     Wx, Wh, WxTp, WhQ, wscale);
  hipLaunchKernelGGL(rec_k, dim3(BB), dim3(512), 0, stream,
                     x, dur, rep, WxTp, WhQ, wscale, bias, out);
}

// Round 21
// 154.913 us; speedup vs baseline: 1.4524x; 1.0081x over previous
//
#include <hip/hip_runtime.h>

#define TT 200
#define BB 256
#define DD 128
#define HH 128
#define NG 896    // 7*H semantic gate dim (gate-major: col = g*128 + u)
#define NGP 1024  // padded xg: pcol = u*8 + gate, gate 7 = zero pad

typedef _Float16 half8 __attribute__((ext_vector_type(8)));
typedef _Float16 half4 __attribute__((ext_vector_type(4)));
typedef float float4v __attribute__((ext_vector_type(4)));
typedef int int4v __attribute__((ext_vector_type(4)));

__device__ __forceinline__ float rcpf_(float x) { return __builtin_amdgcn_rcpf(x); }
__device__ __forceinline__ float sigmoidf_(float x) { return rcpf_(1.f + __expf(-x)); }
__device__ __forceinline__ float tanhf_(float x) { return 1.f - 2.f * rcpf_(__expf(2.f * x) + 1.f); }
// softplus(x) = max(x,0) + ln(1+exp(-|x|))
__device__ __forceinline__ float softplusf_(float x) {
  return fmaxf(x, 0.f) + 0.69314718056f * __log2f(1.f + __expf(-fabsf(x)));
}

// Merged prep, all-coalesced:
//  blocks [0,28): LDS-tiled Wx transpose (128k x 32j tile) -> WxTp[pcol][k]
//  block 28:      bias_p
//  blocks [29,43): W_h i8 per-column quantization (r15 parallel version)
__global__ __launch_bounds__(256) void prep_k(const float* __restrict__ Wx,
    const float* __restrict__ bias, const float* __restrict__ Wh,
    _Float16* __restrict__ WxTp, float* __restrict__ bias_p,
    char* __restrict__ WhQ, float* __restrict__ wscale) {
  int bx = blockIdx.x;
  int tid = threadIdx.x;
  if (bx < 28) {  // transpose tile: j in [j0, j0+32), all 128 k
    __shared__ _Float16 Tld[32][136];
    int j0 = bx * 32;
    int jo = tid & 31, kb = tid >> 5;  // 8 k-rows per iter
#pragma unroll
    for (int it = 0; it < 16; ++it) {
      int k = kb + it * 8;
      Tld[jo][k] = (_Float16)Wx[(size_t)k * NG + j0 + jo];  // coalesced over jo
    }
    __syncthreads();
    int g = j0 >> 7, u0 = j0 & 127;
    int jw = tid >> 3, kq = (tid & 7) * 16;
    int pcol = (u0 + jw) * 8 + g;
    *(half8*)&WxTp[(size_t)pcol * DD + kq] = *(const half8*)&Tld[jw][kq];
    *(half8*)&WxTp[(size_t)pcol * DD + kq + 8] = *(const half8*)&Tld[jw][kq + 8];
    return;
  }
  if (bx == 28) {  // bias_p (+ zero pad gate 7)
#pragma unroll
    for (int i = 0; i < 4; ++i) {
      int pcol = tid * 4 + i;
      int u = pcol >> 3, g = pcol & 7;
      bias_p[pcol] = (g < 7) ? bias[g * HH + u] : 0.f;
    }
    return;
  }
  // quant part: 64 cols per block
  __shared__ float redmax[4][64];
  int c = tid & 63, kq = tid >> 6;
  int col = (bx - 29) * 64 + c;
  float v[32];
  float m = 0.f;
#pragma unroll
  for (int i = 0; i < 32; ++i) {
    v[i] = Wh[(size_t)(kq * 32 + i) * NG + col];
    m = fmaxf(m, fabsf(v[i]));
  }
  redmax[kq][c] = m;
  __syncthreads();
  float mm = fmaxf(fmaxf(redmax[0][c], redmax[1][c]),
                   fmaxf(redmax[2][c], redmax[3][c]));
  mm = mm > 0.f ? mm : 1.f;
  float inv = 127.f * rcpf_(mm);
  char q[32];
#pragma unroll
  for (int i = 0; i < 32; ++i) q[i] = (char)__float2int_rn(v[i] * inv);
#pragma unroll
  for (int i = 0; i < 8; ++i)
    *(int*)&WhQ[(size_t)col * DD + kq * 32 + i * 4] = *(int*)&q[i * 4];
  if (kq == 0) wscale[col] = mm * (1.f / 127.f);
}

// xg GEMM (r14 coalesced writes + r16 skip-store of rows rec never reads)
__global__ __launch_bounds__(256, 2) void xg_gemm_k(const float* __restrict__ x,
    const _Float16* __restrict__ WxTp, const float* __restrict__ bias_p,
    const int* __restrict__ rep, _Float16* __restrict__ xg, int t0) {
  int mt = blockIdx.x;
  __shared__ _Float16 Ald[128][136];
  __shared__ _Float16 Bld[128][136];
  __shared__ int tends[128];
  int tid = threadIdx.x;
  int G0 = mt * 128;
  int t = t0 + (G0 >> 8);
  int b0 = G0 & 255;
  if (tid < 128) tends[tid] = rep[b0 + tid];
  {
    int r = tid >> 5, kq = (tid & 31) << 2;
#pragma unroll
    for (int it = 0; it < 16; ++it) {
      int row = r + it * 8;
      float4v xv = *(const float4v*)(x + ((size_t)(b0 + row) * TT + t) * DD + kq);
      half4 h4 = {(_Float16)xv[0], (_Float16)xv[1], (_Float16)xv[2], (_Float16)xv[3]};
      *(half4*)&Ald[row][kq] = h4;
    }
  }
  __syncthreads();
  int wv = tid >> 6, l = tid & 63, lr = l & 15, lk8 = (l >> 4) << 3;
  half8 af[2][4];
#pragma unroll
  for (int mf = 0; mf < 2; ++mf)
#pragma unroll
    for (int kk = 0; kk < 4; ++kk)
      af[mf][kk] = *(const half8*)&Ald[wv * 32 + mf * 16 + lr][kk * 32 + lk8];
  int r4 = (l >> 4) << 2;

  for (int nt = 0; nt < 8; ++nt) {
    for (int i = tid; i < 128 * 16; i += 256) {
      int r = i >> 4, c8 = (i & 15) << 3;
      *(half8*)&Bld[r][c8] = *(const half8*)(WxTp + (size_t)(nt * 128 + r) * DD + c8);
    }
    __syncthreads();
    float4v acc[2][8];
#pragma unroll
    for (int a = 0; a < 2; ++a)
#pragma unroll
      for (int q = 0; q < 8; ++q) acc[a][q] = (float4v){0.f, 0.f, 0.f, 0.f};
#pragma unroll
    for (int kk = 0; kk < 4; ++kk) {
#pragma unroll
      for (int nf = 0; nf < 8; ++nf) {
        half8 bv = *(const half8*)&Bld[nf * 16 + lr][kk * 32 + lk8];
        acc[0][nf] = __builtin_amdgcn_mfma_f32_16x16x32_f16(af[0][kk], bv, acc[0][nf], 0, 0, 0);
        acc[1][nf] = __builtin_amdgcn_mfma_f32_16x16x32_f16(af[1][kk], bv, acc[1][nf], 0, 0, 0);
      }
    }
#pragma unroll
    for (int nf = 0; nf < 8; ++nf) {
      int colL = nf * 16 + lr;
      float bv = bias_p[nt * 128 + colL];
#pragma unroll
      for (int mf = 0; mf < 2; ++mf) {
        int rowL = wv * 32 + mf * 16 + r4;
#pragma unroll
        for (int rr = 0; rr < 4; ++rr)
          Ald[rowL + rr][colL] = (_Float16)(acc[mf][nf][rr] + bv);
      }
    }
    __syncthreads();
#pragma unroll
    for (int it = 0; it < 8; ++it) {
      int slot = tid + it * 256;
      int row = slot >> 4, cg = slot & 15;
      if (t <= tends[row]) {  // skip rows rec never reads
        half8 v = *(const half8*)&Ald[row][cg * 8];
        *(half8*)&xg[(size_t)(G0 + row) * NGP + nt * 128 + cg * 8] = v;
      }
    }
  }
}

// MFMA recurrence, i8 weights+h — session champion. 1 block/sample,
// 512 threads (8 waves, 2/SIMD, 256-reg budget keeps wbq resident), one
// __syncthreads per step, 8-batch xg register prefetch.
// Structural laws established this session:
//  - weight residency requires <=8-wave blocks (r7/r8/r16: bigger blocks cap
//    regs at 128/wave -> spill or re-fetch);
//  - the ~450cy chain/barrier residue resists vmcnt batching (r9), stagger
//    (r14), TLP (r7/r8/r16), and producer fusion (r18-r20: parity at best);
//  - i8 16x16x64 MFMA halves the h@W_h pipe time vs f16 (r12: 165->118 us).
__global__ __launch_bounds__(512, 2) void rec_k(const _Float16* __restrict__ xg,
    const float* __restrict__ dur, const int* __restrict__ rep,
    const char* __restrict__ WhQ, const float* __restrict__ wscale,
    float* __restrict__ out,
    char* __restrict__ st_h, float* __restrict__ st_c, float* __restrict__ st_cb,
    int t0, int t1) {
  int b = blockIdx.x, j = threadIdx.x;
  int tend = rep[b];
  if (t0 > tend) return;  // block-uniform
  int tstop = min(t1 - 1, tend);
  __shared__ __align__(16) char hq[2][HH];  // i8 h, double-buffered
  __shared__ float dlds[TT];
  int w = j >> 6, l = j & 63, lr = l & 15, lg = l >> 4;
  int u = w * 16 + lr;

  int4v wbq[7][2];
#pragma unroll
  for (int g = 0; g < 7; ++g)
#pragma unroll
    for (int m = 0; m < 2; ++m)
      wbq[g][m] = *(const int4v*)(WhQ + (size_t)(g * HH + u) * DD + m * 64 + lg * 16);
  float sg[7];
#pragma unroll
  for (int g = 0; g < 7; ++g) sg[g] = wscale[g * HH + u] * (1.f / 127.f);
  for (int i = j; i < TT; i += 512) dlds[i] = dur[b * TT + i];
  float c_s = 0.f, cb_s = 0.f;
  if (lg == 0) {
    hq[0][u] = (t0 == 0) ? (char)0 : st_h[b * HH + u];
    hq[1][u] = (char)0;
  }
  if (t0 != 0) {
    c_s = st_c[b * HH + u];
    cb_s = st_cb[b * HH + u];
  }
  __syncthreads();

  const _Float16* xgp = xg + (size_t)b * NGP + u * 8;  // + step*stp, aligned 16B
  const size_t stp = (size_t)BB * NGP;
  half8 cur[8], nxt[8];
#pragma unroll
  for (int i = 0; i < 8; ++i)
    cur[i] = *(const half8*)(xgp + (size_t)(min(t0 + i, tstop) - t0) * stp);
  char hqsave = 0;

#define STEP(T, CUR, PIN, POUT)                                                  \
  do {                                                                           \
    float dt = dlds[T];                                                          \
    int4v aq0 = *(const int4v*)&hq[PIN][lg * 16];                                \
    int4v aq1 = *(const int4v*)&hq[PIN][64 + lg * 16];                           \
    int4v acc[7];                                                                \
    _Pragma("unroll") for (int g = 0; g < 7; ++g) acc[g] = (int4v){0, 0, 0, 0};  \
    _Pragma("unroll") for (int g = 0; g < 7; ++g)                                \
        acc[g] = __builtin_amdgcn_mfma_i32_16x16x64_i8(aq0, wbq[g][0], acc[g], 0, 0, 0); \
    _Pragma("unroll") for (int g = 0; g < 7; ++g)                                \
        acc[g] = __builtin_amdgcn_mfma_i32_16x16x64_i8(aq1, wbq[g][1], acc[g], 0, 0, 0); \
    float gv[7];                                                                 \
    _Pragma("unroll") for (int g = 0; g < 7; ++g)                                \
        gv[g] = (float)acc[g][0] * sg[g] + (float)CUR[g];                        \
    float iv = sigmoidf_(gv[0]), fv = sigmoidf_(gv[1]);                          \
    float zv = tanhf_(gv[2]), ov = sigmoidf_(gv[3]);                             \
    float ibv = sigmoidf_(gv[4]), fbv = sigmoidf_(gv[5]);                        \
    float dv = softplusf_(gv[6]);                                                \
    float cc = fv * c_s + iv * zv;                                               \
    cb_s = fbv * cb_s + ibv * zv;                                                \
    float cn = cb_s + (cc - cb_s) * __expf(-dv * dt);                            \
    float hn = ov * tanhf_(cn);                                                  \
    c_s = cn;                                                                    \
    char hb = (char)__float2int_rn(hn * 127.f);                                  \
    hqsave = hb;                                                                 \
    if (lg == 0) {                                                               \
      if ((T) == tend) {                                                         \
        out[b * HH + u] = hn;                                                    \
        out[BB * HH + b * HH + u] = cn;                                          \
      }                                                                          \
      hq[POUT][u] = hb;                                                          \
    }                                                                            \
    __syncthreads();                                                             \
  } while (0)

  for (int tb = t0; tb <= tstop; tb += 8) {
#pragma unroll
    for (int i = 0; i < 8; ++i)
      nxt[i] = *(const half8*)(xgp + (size_t)(min(tb + 8 + i, tstop) - t0) * stp);
    STEP(tb, cur[0], 0, 1);
    if (tb + 1 <= tstop) STEP(tb + 1, cur[1], 1, 0);
    if (tb + 2 <= tstop) STEP(tb + 2, cur[2], 0, 1);
    if (tb + 3 <= tstop) STEP(tb + 3, cur[3], 1, 0);
    if (tb + 4 <= tstop) STEP(tb + 4, cur[4], 0, 1);
    if (tb + 5 <= tstop) STEP(tb + 5, cur[5], 1, 0);
    if (tb + 6 <= tstop) STEP(tb + 6, cur[6], 0, 1);
    if (tb + 7 <= tstop) STEP(tb + 7, cur[7], 1, 0);
#pragma unroll
    for (int i = 0; i < 8; ++i) cur[i] = nxt[i];
  }
#undef STEP

  if (tstop < tend && lg == 0) {  // save state for next chunk
    st_h[b * HH + u] = hqsave;
    st_c[b * HH + u] = c_s;
    st_cb[b * HH + u] = cb_s;
  }
}

extern "C" void kernel_launch(void* const* d_in, const int* in_sizes, int n_in,
                              void* d_out, int out_size, void* d_ws, size_t ws_size,
                              hipStream_t stream) {
  const float* x = (const float*)d_in[0];
  const float* dur = (const float*)d_in[1];
  const int* rep = (const int*)d_in[2];
  const float* Wx = (const float*)d_in[3];
  const float* Wh = (const float*)d_in[4];
  const float* bias = (const float*)d_in[5];
  float* out = (float*)d_out;
  char* ws = (char*)d_ws;

  size_t off = 0;
  _Float16* WxTp = (_Float16*)(ws + off); off += (size_t)NGP * DD * 2;
  float* bias_p = (float*)(ws + off); off += (size_t)NGP * 4;
  char* WhQ = (char*)(ws + off); off += (size_t)NG * DD;
  float* wscale = (float*)(ws + off); off += (size_t)NG * 4;
  char* st_h = (char*)(ws + off); off += (size_t)BB * HH;
  float* st_c = (float*)(ws + off); off += (size_t)BB * HH * 4;
  float* st_cb = (float*)(ws + off); off += (size_t)BB * HH * 4;
  off = (off + 255) & ~(size_t)255;
  _Float16* xgbuf = (_Float16*)(ws + off);

  size_t avail = ws_size > off ? ws_size - off : 0;
  size_t perT = (size_t)BB * NGP * 2;
  int Tc = (int)(avail / perT);
  if (Tc > TT) Tc = TT;
  if (Tc < 1) Tc = 1;

  hipLaunchKernelGGL(prep_k, dim3(29 + NG / 64), dim3(256), 0, stream,
                     Wx, bias, Wh, WxTp, bias_p, WhQ, wscale);
  for (int t0 = 0; t0 < TT; t0 += Tc) {
    int t1 = t0 + Tc;
    if (t1 > TT) t1 = TT;
    int mtiles = (t1 - t0) * BB / 128;
    hipLaunchKernelGGL(xg_gemm_k, dim3(mtiles), dim3(256), 0, stream,
                       x, WxTp, bias_p, rep, xgbuf, t0);
    hipLaunchKernelGGL(rec_k, dim3(BB), dim3(512), 0, stream,
                       xgbuf, dur, rep, WhQ, wscale, out, st_h, st_c, st_cb, t0, t1);
  }
}